// Round 9
// baseline (64.811 us; speedup 1.0000x reference)
//
#include <hip/hip_runtime.h>
#include <hip/hip_bf16.h>

#define GK 512
#define GN 128
#define GRROWS 131072   // 4096 batch * 32 blocks

typedef float  f32x4  __attribute__((ext_vector_type(4)));
typedef __bf16 bf16x8 __attribute__((ext_vector_type(8)));
typedef unsigned int u32x4 __attribute__((ext_vector_type(4)));

typedef __attribute__((address_space(3))) unsigned int lds_uint;
typedef __attribute__((address_space(1))) unsigned int glb_uint;

__device__ __forceinline__ void gload_lds16(const void* g, void* l) {
    // direct global->LDS DMA, 16B/lane, LDS dest = wave-uniform base + lane*16
    __builtin_amdgcn_global_load_lds((const glb_uint*)g, (lds_uint*)l, 16, 0, 0);
}

// ---------------------------------------------------------------------------
// Kernel 1 (unchanged, R8-proven): k<256 half of W in MFMA fragment order.
// wfrag[t][f][lane][j], t=0..7, f=0..7:
//   W[k][n], n = f*16+(lane&15), g=lane>>4, k = t*32+(j>>2)*16+g*4+(j&3)
// W[k][n]=A[n][k]: k<256: n<64 -> cos, n>=64 -> sin (ang=-2pi*pv[n&63]*k/256)
// Symmetry (k->k+256): frag_full(t+8,f) = -frag(t,f+4) [f<4], +frag(t,f-4) [f>=4]
// ---------------------------------------------------------------------------
__global__ void build_w_frags(const float* __restrict__ pv, __bf16* __restrict__ wfrag) {
    int tid = blockIdx.x * blockDim.x + threadIdx.x;
    if (tid >= 8 * 8 * 64) return;
    int lane = tid & 63;
    int f    = (tid >> 6) & 7;
    int t    = tid >> 9;
    int n    = f * 16 + (lane & 15);
    int g    = lane >> 4;
    bool ph  = (n >= 64);
    float pq = pv[n & 63];
    const float step = -0.02454369260617025967f; // -2*pi/256
    bf16x8 v;
#pragma unroll
    for (int j = 0; j < 8; ++j) {
        int k  = t * 32 + ((j >> 2) << 4) + g * 4 + (j & 3);
        float ang = pq * (float)k * step;
        float s, c;
        sincosf(ang, &s, &c);
        v[j] = (__bf16)(ph ? s : c);
    }
    *(bf16x8*)(wfrag + (size_t)tid * 8) = v;
}

// ---------------------------------------------------------------------------
// Kernel 2: wave-private global_load_lds pipeline.
// Grid 256 (1 block/CU), 1024 thr = 16 waves; wave = 16 rows x 128 cols.
// Block covers 512 rows = 2 stripes; 32 X-tiles total (tile = 16 rows x 32 k).
// LDS: W half 64KB + per-wave X double-buffer (2 x 2KB) x 16 = 128KB.
// Per-wave pipeline (NO barriers after W-init): stage tt+2 -> vmcnt(2) ->
// compute tt. X staged with XOR-swizzled GLOBAL source (chunk = slot^(row&7))
// so swizzled ds_reads are bank-conflict-free despite the linear LDS dest.
// Symmetric W: tile kt>=8 reuses frag(kt-8, f^4) with sign folded into X.
// ---------------------------------------------------------------------------
__global__ __launch_bounds__(1024, 4) void analog_gemm(const float* __restrict__ X,
                                                       const __bf16* __restrict__ W,
                                                       float* __restrict__ out) {
    __shared__ __align__(16) unsigned char smem[131072];
    __bf16* lw        = (__bf16*)smem;          // 64KB W frags
    unsigned char* lx = smem + 65536;           // 64KB X tiles

    const int tid  = threadIdx.x;
    const int lane = tid & 63;
    const int wave = tid >> 6;        // 0..15
    const int lr   = lane & 15;
    const int g    = lane >> 4;       // 0..3

    // ---- stage W half: 4096 x 16B chunks, linear ----
#pragma unroll
    for (int i = 0; i < 4; ++i)
        gload_lds16((const char*)W + (size_t)(i * 1024 + tid) * 16,
                    smem + (i * 1024 + tid) * 16);

    const long blkrow = (long)blockIdx.x * 512;
    unsigned char* mybuf = lx + wave * 4096;          // this wave's 2x2KB
    const int srow = lane >> 3;                       // staging row-in-8 (0..7)
    const int schunk = (lane & 7) ^ srow;             // swizzled global chunk

    // STAGE(tt): stage tile tt (kt=tt&15, stripe rt=tt>>4) into mybuf[tt&1]
#define STAGE(tt) do {                                                          \
        int kt_ = (tt) & 15, rt_ = (tt) >> 4;                                   \
        long r0_ = blkrow + rt_ * 256 + wave * 16;                              \
        const char* gs_ = (const char*)X + kt_ * 128 + (size_t)schunk * 16;     \
        gload_lds16(gs_ + (r0_ + srow) * 2048,       mybuf + ((tt)&1) * 2048);  \
        gload_lds16(gs_ + (r0_ + 8 + srow) * 2048,   mybuf + ((tt)&1) * 2048 + 1024); \
    } while (0)

    STAGE(0);
    STAGE(1);
    // wait: only tile1's 2 loads outstanding -> W + tile0 landed (per wave)
    asm volatile("s_waitcnt vmcnt(2)" ::: "memory");
    __builtin_amdgcn_s_barrier();     // all waves' W chunks visible

    const bf16x8* wp = (const bf16x8*)lw + lane;   // + (kt*8+f)*64

    f32x4 acc[8];
#pragma unroll
    for (int f = 0; f < 8; ++f) acc[f] = (f32x4)0.0f;

    // swizzled read offsets (constant per lane)
    const int sa = ((g ^ (lr & 7)) << 4);           // xa slot byte
    const int sb = (((g + 4) ^ (lr & 7)) << 4);     // xb slot byte

#pragma unroll
    for (int tt = 0; tt < 32; ++tt) {
        if (tt > 0) {
            if (tt < 31) asm volatile("s_waitcnt vmcnt(2)" ::: "memory");
            else         asm volatile("s_waitcnt vmcnt(0)" ::: "memory");
        }
        const unsigned char* xbuf = mybuf + (tt & 1) * 2048;
        f32x4 xa = *(const f32x4*)(xbuf + lr * 128 + sa);
        f32x4 xb = *(const f32x4*)(xbuf + lr * 128 + sb);

        bf16x8 b;
#pragma unroll
        for (int j = 0; j < 4; ++j) { b[j] = (__bf16)xa[j]; b[4 + j] = (__bf16)xb[j]; }

        const int kt = tt & 15;
        if (kt < 8) {
#pragma unroll
            for (int f = 0; f < 8; ++f) {
                bf16x8 w = wp[(kt * 8 + f) * 64];
                acc[f] = __builtin_amdgcn_mfma_f32_16x16x32_bf16(w, b, acc[f], 0, 0, 0);
            }
        } else {
            u32x4 u = __builtin_bit_cast(u32x4, b);
#pragma unroll
            for (int j = 0; j < 4; ++j) u[j] ^= 0x80008000u;
            bf16x8 bn = __builtin_bit_cast(bf16x8, u);
#pragma unroll
            for (int f = 0; f < 4; ++f) {
                bf16x8 w = wp[((kt - 8) * 8 + f + 4) * 64];
                acc[f] = __builtin_amdgcn_mfma_f32_16x16x32_bf16(w, bn, acc[f], 0, 0, 0);
            }
#pragma unroll
            for (int f = 4; f < 8; ++f) {
                bf16x8 w = wp[((kt - 8) * 8 + f - 4) * 64];
                acc[f] = __builtin_amdgcn_mfma_f32_16x16x32_bf16(w, b, acc[f], 0, 0, 0);
            }
        }

        if (kt == 15) {   // end of a stripe: store 16x128 wave tile
            int rt = tt >> 4;
            float* op = out + (blkrow + rt * 256 + wave * 16 + lr) * (long)GN + g * 4;
#pragma unroll
            for (int f = 0; f < 8; ++f)
                __builtin_nontemporal_store(acc[f], (f32x4*)(op + f * 16));
            if (tt == 15) {
#pragma unroll
                for (int f = 0; f < 8; ++f) acc[f] = (f32x4)0.0f;
            }
        }

        if (tt + 2 < 32) {
            // ds_reads of this tile must land before overwriting its buffer
            asm volatile("s_waitcnt lgkmcnt(0)" ::: "memory");
            STAGE(tt + 2);
        }
    }
#undef STAGE
}

extern "C" void kernel_launch(void* const* d_in, const int* in_sizes, int n_in,
                              void* d_out, int out_size, void* d_ws, size_t ws_size,
                              hipStream_t stream) {
    const float* x  = (const float*)d_in[0];
    const float* pv = (const float*)d_in[1];
    float* out      = (float*)d_out;
    __bf16* wfrag   = (__bf16*)d_ws;   // 8*8*64*8*2 = 65536 bytes used

    hipLaunchKernelGGL(build_w_frags, dim3(16), dim3(256), 0, stream, pv, wfrag);
    hipLaunchKernelGGL(analog_gemm, dim3(256), dim3(1024), 0, stream, x, wfrag, out);
}